// Round 14
// baseline (608.370 us; speedup 1.0000x reference)
//
#include <hip/hip_runtime.h>
#include <hip/hip_bf16.h>

typedef __attribute__((ext_vector_type(8))) short short8v;
typedef __attribute__((ext_vector_type(4))) float f32x4;
typedef __attribute__((ext_vector_type(8))) unsigned short us8;
typedef const __attribute__((address_space(1))) void* gas_t;
typedef __attribute__((address_space(3))) void* las_t;

__device__ __forceinline__ unsigned short f2bf(float f) {
  union { __hip_bfloat16 h; unsigned short u; } c;
  c.h = __float2bfloat16(f);
  return c.u;
}
__device__ __forceinline__ unsigned int f2bf2(float lo, float hi) {
  union { __hip_bfloat162 h; unsigned int u; } c;
  c.h = __float22bfloat162_rn(make_float2(lo, hi));
  return c.u;
}

// WA = (Wq@Wk^T)/16, WB = Wv@Wo, wb2 = (Wq@bk)/16, cq = (bq@Wk^T)/16,
// cv = bv@Wo, cb = (bk.bq)/16
__global__ __launch_bounds__(256) void make_w(
    const float* __restrict__ Wq, const float* __restrict__ Wk,
    const float* __restrict__ Wv, const float* __restrict__ Wo,
    const float* __restrict__ bq, const float* __restrict__ bk,
    const float* __restrict__ bv, float* __restrict__ WA,
    float* __restrict__ WB, float* __restrict__ wb2,
    float* __restrict__ cq, float* __restrict__ cv, float* __restrict__ cb) {
  __shared__ float wq[256], wv[256], bqs[256], bvs[256];
  const int i = blockIdx.x, t = threadIdx.x;
  wq[t] = Wq[i * 256 + t];
  wv[t] = Wv[i * 256 + t];
  bqs[t] = bq[t];
  bvs[t] = bv[t];
  __syncthreads();
  float sa = 0.f, sb = 0.f;
#pragma unroll 8
  for (int d = 0; d < 256; d++) {
    sa = fmaf(wq[d], Wk[t * 256 + d], sa);  // WA[i][t]
    sb = fmaf(wv[d], Wo[d * 256 + t], sb);  // WB[i][t]
  }
  WA[i * 256 + t] = sa * 0.0625f;
  WB[i * 256 + t] = sb;
  if (t == 0) {
    float s = 0.f;
#pragma unroll 8
    for (int d = 0; d < 256; d++) s = fmaf(wq[d], bk[d], s);
    wb2[i] = s * 0.0625f;
  }
  if (i == 0) {
    float s1 = 0.f, s2 = 0.f;
#pragma unroll 8
    for (int d = 0; d < 256; d++) {
      s1 = fmaf(bqs[d], Wk[t * 256 + d], s1);
      s2 = fmaf(bvs[d], Wo[d * 256 + t], s2);
    }
    cq[t] = s1 * 0.0625f;
    cv[t] = s2;
    if (t == 0) {
      float s = 0.f;
      for (int d = 0; d < 256; d++) s = fmaf(bk[d], bqs[d], s);
      cb[0] = s * 0.0625f;
    }
  }
}

// ebn[b][n] = exp(hs[b][n]@wb2 + cb)
__global__ __launch_bounds__(256) void bn_k(
    const float* __restrict__ hs, const float* __restrict__ wb2,
    const float* __restrict__ cb, float* __restrict__ ebn) {
  __shared__ float w2s[256];
  const int b = blockIdx.x, t = threadIdx.x;
  w2s[t] = wb2[t];
  __syncthreads();
  const float* row = hs + (size_t)(b * 256 + t) * 256;
  float s = cb[0];
#pragma unroll 8
  for (int d = 0; d < 256; d++) s = fmaf(row[d], w2s[d], s);
  ebn[b * 256 + t] = __expf(s);
}

// A-operand panels, chunk-major, MFMA-A-fragment-contiguous:
//   chunk layout = [tile:16][lhi:4][l16:16][j:8] bf16 (16KB), lane reads 16B
//   at tile*1024B + lane*16B.
// W2c: element (n,d): kc=d>>5, tile=n>>4, lhi=(d>>3)&3, l16=n&15, j=d&7
// V2c: element (c,n): kc=n>>5, tile=c>>4, lhi=(n>>3)&3, l16=c&15, j=n&7
//      (scaled by ebn[n])
__global__ __launch_bounds__(256) void prep2(
    const float* __restrict__ hs, const float* __restrict__ WA,
    const float* __restrict__ WB, const float* __restrict__ cq,
    const float* __restrict__ cv, const float* __restrict__ ebn,
    unsigned short* __restrict__ W2c, unsigned short* __restrict__ V2c) {
  __shared__ float rows[8][256];
  const int tid = threadIdx.x;
  const int g0 = blockIdx.x * 8;
#pragma unroll
  for (int j = 0; j < 8; j++) rows[j][tid] = hs[(size_t)(g0 + j) * 256 + tid];
  __syncthreads();
  const float cqv = cq[tid], cvv = cv[tid];
  float aq[8], av[8];
#pragma unroll
  for (int j = 0; j < 8; j++) { aq[j] = cqv; av[j] = cvv; }
#pragma unroll 8
  for (int i = 0; i < 256; i++) {
    const float wa = WA[i * 256 + tid];
    const float wb = WB[i * 256 + tid];
#pragma unroll
    for (int j = 0; j < 8; j++) {
      aq[j] = fmaf(rows[j][i], wa, aq[j]);
      av[j] = fmaf(rows[j][i], wb, av[j]);
    }
  }
  const int bb = g0 >> 8, n0 = g0 & 255;
  // W2c: thread holds (n = n0..n0+7, d = tid)
  {
    const int kc = tid >> 5, lh = (tid >> 3) & 3, j8 = tid & 7;
    unsigned short* dst = W2c + bb * 65536 + kc * 8192 + (n0 >> 4) * 512 +
                          lh * 128 + (n0 & 15) * 8 + j8;
#pragma unroll
    for (int jj = 0; jj < 8; jj++) dst[jj * 8] = f2bf(aq[jj]);
  }
  // V2c: thread holds (c = tid, n = n0..n0+7), scaled by ebn[n]
  {
    const int kc = n0 >> 5, lh = (n0 >> 3) & 3;
    us8 vp;
#pragma unroll
    for (int j = 0; j < 8; j++)
      vp[j] = f2bf(av[j] * ebn[bb * 256 + n0 + j]);
    *(us8*)(V2c + bb * 65536 + kc * 8192 + (tid >> 4) * 512 + lh * 128 +
            (tid & 15) * 8) = vp;
  }
}

// Stage one wave-eighth (2KB) of a 16KB A-chunk into LDS (identity copy).
__device__ __forceinline__ void stage8(const unsigned short* src,
                                       unsigned short* lds, int lane) {
#pragma unroll
  for (int i = 0; i < 2; i++)
    __builtin_amdgcn_global_load_lds((gas_t)(src + i * 512 + lane * 8),
                                     (las_t)(lds + i * 512), 16, 0, 0);
}

// Swapped-operand fused kernel, 128 rows/block (8 waves x 16 rows), 4-deep
// chunk ring with counted vmcnt (stage-3-ahead). scores^T = mfma(W2, S^T);
// P stays in registers; o^T = mfma(V2^T, P^T).
__global__ __launch_bounds__(512, 4) void pair_attn12(
    const float* __restrict__ S, const float* __restrict__ bo,
    const float* __restrict__ gamma, const float* __restrict__ beta,
    const float* __restrict__ ebn, const unsigned short* __restrict__ W2c,
    const unsigned short* __restrict__ V2c, float* __restrict__ out) {
  __shared__ unsigned short sB[4][8192];  // 4 x 16KB A-chunk ring
  __shared__ unsigned short sE[4096];     // ebn A-panel [kc:8][lhi][l16][j]

  const int tid = threadIdx.x;
  const int w = tid >> 6;        // wave 0..7
  const int lane = tid & 63;
  const int l16 = lane & 15;
  const int lhi = lane >> 4;
  // XCD-pinned batch: 4096 wgs = 8 batches x 512 tiles (round-robin)
  const int bid = blockIdx.x;
  const int bat = bid & 7;
  const int idx = bid >> 3;      // 0..511
  const int rblk = idx & 1;
  const int lrow = idx >> 1;

  const size_t base = ((size_t)((bat * 256 + lrow) * 256 + rblk * 128)) * 256;
  const float* Srow = S + base + (size_t)(w * 16 + l16) * 256;  // lane's row

  // ---- S B-frags straight from global (row r, d = kc*32 + lhi*8 + j)
  short8v sf[8];
#pragma unroll
  for (int kc = 0; kc < 8; kc++) {
    const float4 u = *(const float4*)(Srow + kc * 32 + lhi * 8);
    const float4 v = *(const float4*)(Srow + kc * 32 + lhi * 8 + 4);
    us8 p;
    unsigned int* pu = (unsigned int*)&p;
    pu[0] = f2bf2(u.x, u.y);
    pu[1] = f2bf2(u.z, u.w);
    pu[2] = f2bf2(v.x, v.y);
    pu[3] = f2bf2(v.z, v.w);
    sf[kc] = *(short8v*)&p;
  }

  // ---- ebn A-panel fill (value ebn[n], replicated over l16)
  if (tid < 256) {
    const unsigned short eb = f2bf(ebn[bat * 256 + tid]);
    unsigned short* d0 =
        sE + (tid >> 5) * 512 + ((tid >> 3) & 3) * 128 + (tid & 7);
#pragma unroll
    for (int t = 0; t < 16; t++) d0[t * 8] = eb;
  }

  asm volatile("s_waitcnt lgkmcnt(0)" ::: "memory");
  asm volatile("s_waitcnt vmcnt(0)" ::: "memory");
  __builtin_amdgcn_sched_barrier(0);

  const unsigned short* W2b = W2c + (size_t)bat * 65536;
  const unsigned short* V2b = V2c + (size_t)bat * 65536;

  // prologue: stage chunks 0,1,2 (W)
  stage8(W2b + 0 * 8192 + w * 1024, &sB[0][w * 1024], lane);
  stage8(W2b + 1 * 8192 + w * 1024, &sB[1][w * 1024], lane);
  stage8(W2b + 2 * 8192 + w * 1024, &sB[2][w * 1024], lane);

  f32x4 acc[16];
#pragma unroll
  for (int t = 0; t < 16; t++) acc[t] = (f32x4){0.f, 0.f, 0.f, 0.f};

  // ---- GEMM-A: scores^T[n][r], chunks 0..7 over d; stage chunk q+3
#pragma unroll
  for (int q = 0; q < 8; q++) {
    asm volatile("s_waitcnt vmcnt(4)" ::: "memory");  // chunk q complete
    __builtin_amdgcn_s_barrier();                     // all parts visible
    {
      const int t3 = q + 3;  // next chunk to stage (3 ahead)
      const unsigned short* src = (t3 < 8) ? (W2b + t3 * 8192)
                                           : (V2b + (t3 - 8) * 8192);
      stage8(src + w * 1024, &sB[t3 & 3][w * 1024], lane);
    }
    __builtin_amdgcn_sched_barrier(0);
    const unsigned short* bbuf = &sB[q & 3][0];
#pragma unroll
    for (int nt = 0; nt < 16; nt++) {
      const short8v af = *(const short8v*)(bbuf + nt * 512 + lane * 8);
      acc[nt] =
          __builtin_amdgcn_mfma_f32_16x16x32_bf16(af, sf[q], acc[nt], 0, 0, 0);
    }
  }

  // ---- softmax numerators in-register: p = exp(s), packed bf16 pairs
  unsigned int pkd[32];
#pragma unroll
  for (int nt = 0; nt < 16; nt++) {
    const float p0 = __expf(acc[nt][0]);
    const float p1 = __expf(acc[nt][1]);
    const float p2 = __expf(acc[nt][2]);
    const float p3 = __expf(acc[nt][3]);
    pkd[nt * 2] = f2bf2(p0, p1);
    pkd[nt * 2 + 1] = f2bf2(p2, p3);
  }

  // bpermute source-lane addresses (bytes): src lane = l16 + 16*lhi_s
  const int A0 = (l16 + ((lhi & 1) * 32)) * 4;
  const int A1 = A0 + 64;
  const bool lo = (lhi < 2);

  f32x4 accE = (f32x4){0.f, 0.f, 0.f, 0.f};
#pragma unroll
  for (int t = 0; t < 16; t++) acc[t] = (f32x4){0.f, 0.f, 0.f, 0.f};

  // ---- GEMM-B: o^T[c][r], chunks 8..15 over n; psum via ebn-panel MFMA
#pragma unroll
  for (int qq = 0; qq < 8; qq++) {
    if (qq < 6) {
      asm volatile("s_waitcnt vmcnt(4)" ::: "memory");
    } else if (qq == 6) {
      asm volatile("s_waitcnt vmcnt(2)" ::: "memory");
    } else {
      asm volatile("s_waitcnt vmcnt(0)" ::: "memory");
    }
    __builtin_amdgcn_s_barrier();
    if (qq < 5)  // chunks 11..15 staged here (8,9,10 staged in A-loop)
      stage8(V2b + (qq + 3) * 8192 + w * 1024, &sB[(qq + 3) & 3][w * 1024],
             lane);
    __builtin_amdgcn_sched_barrier(0);
    // P^T B-frag: k = n = qq*32 + lhi*8 + m, from packed regs via bpermute
    const unsigned int e0 = __builtin_amdgcn_ds_bpermute(A0, pkd[4 * qq + 0]);
    const unsigned int o0 = __builtin_amdgcn_ds_bpermute(A0, pkd[4 * qq + 2]);
    const unsigned int e1 = __builtin_amdgcn_ds_bpermute(A0, pkd[4 * qq + 1]);
    const unsigned int o1 = __builtin_amdgcn_ds_bpermute(A0, pkd[4 * qq + 3]);
    const unsigned int e2 = __builtin_amdgcn_ds_bpermute(A1, pkd[4 * qq + 0]);
    const unsigned int o2 = __builtin_amdgcn_ds_bpermute(A1, pkd[4 * qq + 2]);
    const unsigned int e3 = __builtin_amdgcn_ds_bpermute(A1, pkd[4 * qq + 1]);
    const unsigned int o3 = __builtin_amdgcn_ds_bpermute(A1, pkd[4 * qq + 3]);
    union { unsigned int u[4]; short8v v; } bp_;
    bp_.u[0] = lo ? e0 : o0;
    bp_.u[1] = lo ? e1 : o1;
    bp_.u[2] = lo ? e2 : o2;
    bp_.u[3] = lo ? e3 : o3;
    const short8v bp = bp_.v;
    const unsigned short* bbuf = &sB[qq & 3][0];
    const short8v ae = *(const short8v*)(sE + qq * 512 + lane * 8);
    accE = __builtin_amdgcn_mfma_f32_16x16x32_bf16(ae, bp, accE, 0, 0, 0);
#pragma unroll
    for (int ct = 0; ct < 16; ct++) {
      const short8v af = *(const short8v*)(bbuf + ct * 512 + lane * 8);
      acc[ct] =
          __builtin_amdgcn_mfma_f32_16x16x32_bf16(af, bp, acc[ct], 0, 0, 0);
    }
  }
  __builtin_amdgcn_sched_barrier(0);

  // ---- epilogue (all lane-local): o/psum + bo + resid, LN, float4 store
  const float inv = 1.f / accE[0];
  float s1 = 0.f, s2 = 0.f;
#pragma unroll
  for (int ct = 0; ct < 16; ct++) {
    const float4 rz = *(const float4*)(Srow + ct * 16 + lhi * 4);
    const float4 b4 = *(const float4*)(bo + ct * 16 + lhi * 4);
    f32x4 v;
    v[0] = acc[ct][0] * inv + b4.x + rz.x;
    v[1] = acc[ct][1] * inv + b4.y + rz.y;
    v[2] = acc[ct][2] * inv + b4.z + rz.z;
    v[3] = acc[ct][3] * inv + b4.w + rz.w;
#pragma unroll
    for (int g = 0; g < 4; g++) {
      s1 += v[g];
      s2 = fmaf(v[g], v[g], s2);
    }
    acc[ct] = v;
  }
  s1 += __shfl_xor(s1, 16); s2 += __shfl_xor(s2, 16);
  s1 += __shfl_xor(s1, 32); s2 += __shfl_xor(s2, 32);
  const float mean = s1 * (1.f / 256.f);
  const float rstd = rsqrtf(s2 * (1.f / 256.f) - mean * mean + 1e-5f);
  float* Orow = out + base + (size_t)(w * 16 + l16) * 256;
#pragma unroll
  for (int ct = 0; ct < 16; ct++) {
    const float4 g4 = *(const float4*)(gamma + ct * 16 + lhi * 4);
    const float4 be4 = *(const float4*)(beta + ct * 16 + lhi * 4);
    float4 ov;
    ov.x = (acc[ct][0] - mean) * rstd * g4.x + be4.x;
    ov.y = (acc[ct][1] - mean) * rstd * g4.y + be4.y;
    ov.z = (acc[ct][2] - mean) * rstd * g4.z + be4.z;
    ov.w = (acc[ct][3] - mean) * rstd * g4.w + be4.w;
    *(float4*)(Orow + ct * 16 + lhi * 4) = ov;
  }
}

extern "C" void kernel_launch(void* const* d_in, const int* in_sizes, int n_in,
                              void* d_out, int out_size, void* d_ws, size_t ws_size,
                              hipStream_t stream) {
  const float* hs    = (const float*)d_in[0];
  const float* S     = (const float*)d_in[1];
  const float* Wq    = (const float*)d_in[2];
  const float* bq    = (const float*)d_in[3];
  const float* Wk    = (const float*)d_in[4];
  const float* bk    = (const float*)d_in[5];
  const float* Wv    = (const float*)d_in[6];
  const float* bv    = (const float*)d_in[7];
  const float* Wo    = (const float*)d_in[8];
  const float* bo    = (const float*)d_in[9];
  const float* gamma = (const float*)d_in[10];
  const float* beta  = (const float*)d_in[11];

  unsigned short* W2c = (unsigned short*)d_ws;          // 8*256*256 bf16 = 1MB
  unsigned short* V2c = W2c + 8 * 256 * 256;            // 1MB
  float* WA  = (float*)(V2c + 8 * 256 * 256);           // 256KB
  float* WB  = WA + 256 * 256;                          // 256KB
  float* wb2 = WB + 256 * 256;                          // 1KB
  float* cq  = wb2 + 256;
  float* cv  = cq + 256;
  float* cb  = cv + 256;
  float* ebn = cb + 256;                                // 8*256 f32

  make_w<<<256, 256, 0, stream>>>(Wq, Wk, Wv, Wo, bq, bk, bv, WA, WB, wb2, cq,
                                  cv, cb);
  bn_k<<<8, 256, 0, stream>>>(hs, wb2, cb, ebn);
  prep2<<<256, 256, 0, stream>>>(hs, WA, WB, cq, cv, ebn, W2c, V2c);
  pair_attn12<<<4096, 512, 0, stream>>>(S, bo, gamma, beta, ebn, W2c, V2c,
                                        (float*)d_out);
}

// Round 15
// 556.822 us; speedup vs baseline: 1.0926x; 1.0926x over previous
//
#include <hip/hip_runtime.h>
#include <hip/hip_bf16.h>

typedef __attribute__((ext_vector_type(8))) short short8v;
typedef __attribute__((ext_vector_type(4))) float f32x4;
typedef __attribute__((ext_vector_type(8))) unsigned short us8;
typedef const __attribute__((address_space(1))) void* gas_t;
typedef __attribute__((address_space(3))) void* las_t;

__device__ __forceinline__ unsigned short f2bf(float f) {
  union { __hip_bfloat16 h; unsigned short u; } c;
  c.h = __float2bfloat16(f);
  return c.u;
}
__device__ __forceinline__ unsigned int f2bf2(float lo, float hi) {
  union { __hip_bfloat162 h; unsigned int u; } c;
  c.h = __float22bfloat162_rn(make_float2(lo, hi));
  return c.u;
}

// WA = (Wq@Wk^T)/16, WB = Wv@Wo, wb2 = (Wq@bk)/16, cq = (bq@Wk^T)/16,
// cv = bv@Wo, cb = (bk.bq)/16
__global__ __launch_bounds__(256) void make_w(
    const float* __restrict__ Wq, const float* __restrict__ Wk,
    const float* __restrict__ Wv, const float* __restrict__ Wo,
    const float* __restrict__ bq, const float* __restrict__ bk,
    const float* __restrict__ bv, float* __restrict__ WA,
    float* __restrict__ WB, float* __restrict__ wb2,
    float* __restrict__ cq, float* __restrict__ cv, float* __restrict__ cb) {
  __shared__ float wq[256], wv[256], bqs[256], bvs[256];
  const int i = blockIdx.x, t = threadIdx.x;
  wq[t] = Wq[i * 256 + t];
  wv[t] = Wv[i * 256 + t];
  bqs[t] = bq[t];
  bvs[t] = bv[t];
  __syncthreads();
  float sa = 0.f, sb = 0.f;
#pragma unroll 8
  for (int d = 0; d < 256; d++) {
    sa = fmaf(wq[d], Wk[t * 256 + d], sa);  // WA[i][t]
    sb = fmaf(wv[d], Wo[d * 256 + t], sb);  // WB[i][t]
  }
  WA[i * 256 + t] = sa * 0.0625f;
  WB[i * 256 + t] = sb;
  if (t == 0) {
    float s = 0.f;
#pragma unroll 8
    for (int d = 0; d < 256; d++) s = fmaf(wq[d], bk[d], s);
    wb2[i] = s * 0.0625f;
  }
  if (i == 0) {
    float s1 = 0.f, s2 = 0.f;
#pragma unroll 8
    for (int d = 0; d < 256; d++) {
      s1 = fmaf(bqs[d], Wk[t * 256 + d], s1);
      s2 = fmaf(bvs[d], Wo[d * 256 + t], s2);
    }
    cq[t] = s1 * 0.0625f;
    cv[t] = s2;
    if (t == 0) {
      float s = 0.f;
      for (int d = 0; d < 256; d++) s = fmaf(bk[d], bqs[d], s);
      cb[0] = s * 0.0625f;
    }
  }
}

// ebn[b][n] = exp(hs[b][n]@wb2 + cb)
__global__ __launch_bounds__(256) void bn_k(
    const float* __restrict__ hs, const float* __restrict__ wb2,
    const float* __restrict__ cb, float* __restrict__ ebn) {
  __shared__ float w2s[256];
  const int b = blockIdx.x, t = threadIdx.x;
  w2s[t] = wb2[t];
  __syncthreads();
  const float* row = hs + (size_t)(b * 256 + t) * 256;
  float s = cb[0];
#pragma unroll 8
  for (int d = 0; d < 256; d++) s = fmaf(row[d], w2s[d], s);
  ebn[b * 256 + t] = __expf(s);
}

// A-operand panels, chunk-major, MFMA-A-fragment-contiguous:
//   chunk layout = [tile:16][lhi:4][l16:16][j:8] bf16 (16KB), lane reads 16B
//   at tile*1024B + lane*16B.
// W2c: element (n,d): kc=d>>5, tile=n>>4, lhi=(d>>3)&3, l16=n&15, j=d&7
// V2c: element (c,n): kc=n>>5, tile=c>>4, lhi=(n>>3)&3, l16=c&15, j=n&7
//      (scaled by ebn[n])
__global__ __launch_bounds__(256) void prep2(
    const float* __restrict__ hs, const float* __restrict__ WA,
    const float* __restrict__ WB, const float* __restrict__ cq,
    const float* __restrict__ cv, const float* __restrict__ ebn,
    unsigned short* __restrict__ W2c, unsigned short* __restrict__ V2c) {
  __shared__ float rows[8][256];
  const int tid = threadIdx.x;
  const int g0 = blockIdx.x * 8;
#pragma unroll
  for (int j = 0; j < 8; j++) rows[j][tid] = hs[(size_t)(g0 + j) * 256 + tid];
  __syncthreads();
  const float cqv = cq[tid], cvv = cv[tid];
  float aq[8], av[8];
#pragma unroll
  for (int j = 0; j < 8; j++) { aq[j] = cqv; av[j] = cvv; }
#pragma unroll 8
  for (int i = 0; i < 256; i++) {
    const float wa = WA[i * 256 + tid];
    const float wb = WB[i * 256 + tid];
#pragma unroll
    for (int j = 0; j < 8; j++) {
      aq[j] = fmaf(rows[j][i], wa, aq[j]);
      av[j] = fmaf(rows[j][i], wb, av[j]);
    }
  }
  const int bb = g0 >> 8, n0 = g0 & 255;
  // W2c: thread holds (n = n0..n0+7, d = tid)
  {
    const int kc = tid >> 5, lh = (tid >> 3) & 3, j8 = tid & 7;
    unsigned short* dst = W2c + bb * 65536 + kc * 8192 + (n0 >> 4) * 512 +
                          lh * 128 + (n0 & 15) * 8 + j8;
#pragma unroll
    for (int jj = 0; jj < 8; jj++) dst[jj * 8] = f2bf(aq[jj]);
  }
  // V2c: thread holds (c = tid, n = n0..n0+7), scaled by ebn[n]
  {
    const int kc = n0 >> 5, lh = (n0 >> 3) & 3;
    us8 vp;
#pragma unroll
    for (int j = 0; j < 8; j++)
      vp[j] = f2bf(av[j] * ebn[bb * 256 + n0 + j]);
    *(us8*)(V2c + bb * 65536 + kc * 8192 + (tid >> 4) * 512 + lh * 128 +
            (tid & 15) * 8) = vp;
  }
}

// Stage one wave-quarter (4KB) of a 16KB A-chunk into LDS (identity copy).
__device__ __forceinline__ void stage_b(const unsigned short* src,
                                        unsigned short* lds, int lane) {
#pragma unroll
  for (int i = 0; i < 4; i++)
    __builtin_amdgcn_global_load_lds((gas_t)(src + i * 512 + lane * 8),
                                     (las_t)(lds + i * 512), 16, 0, 0);
}

// Swapped-operand fused kernel (R13 shell), ring-4 chunk pipeline with
// counted vmcnt (stage-3-ahead), setprio around MFMA clusters.
// scores^T = mfma(W2, S^T); P in registers; o^T = mfma(V2^T, P^T).
__global__ __launch_bounds__(256, 2) void pair_attn13(
    const float* __restrict__ S, const float* __restrict__ bo,
    const float* __restrict__ gamma, const float* __restrict__ beta,
    const float* __restrict__ ebn, const unsigned short* __restrict__ W2c,
    const unsigned short* __restrict__ V2c, float* __restrict__ out) {
  __shared__ unsigned short sB[4][8192];  // 4 x 16KB A-chunk ring
  __shared__ unsigned short sE[4096];     // ebn A-panel [kc:8][lhi][l16][j]

  const int tid = threadIdx.x;
  const int w = tid >> 6;
  const int lane = tid & 63;
  const int l16 = lane & 15;
  const int lhi = lane >> 4;
  // bijective XCD swizzle: 8192 wgs, 8 XCDs -> each XCD owns one batch
  const int bid = blockIdx.x;
  const int idx = (bid & 7) * 1024 + (bid >> 3);
  const int rblk = idx & 3;
  const int lrow = (idx >> 2) & 255;
  const int bat = idx >> 10;

  const size_t base = ((size_t)((bat * 256 + lrow) * 256 + rblk * 64)) * 256;
  const float* Srow = S + base + (size_t)(w * 16 + l16) * 256;  // lane's row

  // ---- S B-frags straight from global (row r, d = kc*32 + lhi*8 + j)
  short8v sf[8];
#pragma unroll
  for (int kc = 0; kc < 8; kc++) {
    const float4 u = *(const float4*)(Srow + kc * 32 + lhi * 8);
    const float4 v = *(const float4*)(Srow + kc * 32 + lhi * 8 + 4);
    us8 p;
    unsigned int* pu = (unsigned int*)&p;
    pu[0] = f2bf2(u.x, u.y);
    pu[1] = f2bf2(u.z, u.w);
    pu[2] = f2bf2(v.x, v.y);
    pu[3] = f2bf2(v.z, v.w);
    sf[kc] = *(short8v*)&p;
  }

  // ---- ebn A-panel fill (value ebn[n], replicated over l16)
  {
    const unsigned short eb = f2bf(ebn[bat * 256 + tid]);
    unsigned short* d0 =
        sE + (tid >> 5) * 512 + ((tid >> 3) & 3) * 128 + (tid & 7);
#pragma unroll
    for (int t = 0; t < 16; t++) d0[t * 8] = eb;
  }

  asm volatile("s_waitcnt lgkmcnt(0)" ::: "memory");
  asm volatile("s_waitcnt vmcnt(0)" ::: "memory");
  __builtin_amdgcn_sched_barrier(0);

  const unsigned short* W2b = W2c + (size_t)bat * 65536;
  const unsigned short* V2b = V2c + (size_t)bat * 65536;

  // prologue: stage chunks 0,1,2 (W); ring depth 4, 3 chunks in flight
  stage_b(W2b + 0 * 8192 + w * 2048, &sB[0][w * 2048], lane);
  stage_b(W2b + 1 * 8192 + w * 2048, &sB[1][w * 2048], lane);
  stage_b(W2b + 2 * 8192 + w * 2048, &sB[2][w * 2048], lane);

  f32x4 acc[16];
  f32x4 accE = (f32x4){0.f, 0.f, 0.f, 0.f};
  unsigned int pkd[32];
#pragma unroll
  for (int t = 0; t < 16; t++) acc[t] = (f32x4){0.f, 0.f, 0.f, 0.f};

  // bpermute source-lane addresses (bytes): src lane = l16 + 16*lhi_s
  const int A0 = (l16 + ((lhi & 1) * 32)) * 4;
  const int A1 = A0 + 64;
  const bool lo = (lhi < 2);

  // ---- unified 16-chunk pipeline: t=0..7 GEMM-A (over d), 8..15 GEMM-B
#pragma unroll
  for (int t = 0; t < 16; t++) {
    // counted wait: chunk t complete (each wave waits for its own quarter;
    // the barrier then guarantees all quarters are resident).
    if (t < 14) {
      asm volatile("s_waitcnt vmcnt(8)" ::: "memory");
    } else if (t == 14) {
      asm volatile("s_waitcnt vmcnt(4)" ::: "memory");
    } else {
      asm volatile("s_waitcnt vmcnt(0)" ::: "memory");
    }
    __builtin_amdgcn_s_barrier();
    if (t + 3 < 16) {  // stage chunk t+3 into ring slot (t+3)&3
      const int t3 = t + 3;
      const unsigned short* src =
          (t3 < 8) ? (W2b + t3 * 8192) : (V2b + (t3 - 8) * 8192);
      stage_b(src + w * 2048, &sB[t3 & 3][w * 2048], lane);
    }
    __builtin_amdgcn_sched_barrier(0);
    const unsigned short* bbuf = &sB[t & 3][0];

    if (t < 8) {
      // GEMM-A: acc[nt] += mfma(W2_tile_nt, S^T_chunk_t)
      __builtin_amdgcn_s_setprio(1);
#pragma unroll
      for (int nt = 0; nt < 16; nt++) {
        const short8v af = *(const short8v*)(bbuf + nt * 512 + lane * 8);
        acc[nt] = __builtin_amdgcn_mfma_f32_16x16x32_bf16(af, sf[t], acc[nt],
                                                          0, 0, 0);
      }
      __builtin_amdgcn_s_setprio(0);
      if (t == 7) {
        // softmax numerators in-register: p = exp(s), packed bf16 pairs
#pragma unroll
        for (int nt = 0; nt < 16; nt++) {
          const float p0 = __expf(acc[nt][0]);
          const float p1 = __expf(acc[nt][1]);
          const float p2 = __expf(acc[nt][2]);
          const float p3 = __expf(acc[nt][3]);
          pkd[nt * 2] = f2bf2(p0, p1);
          pkd[nt * 2 + 1] = f2bf2(p2, p3);
          acc[nt] = (f32x4){0.f, 0.f, 0.f, 0.f};
        }
      }
    } else {
      const int qq = t - 8;
      // P^T B-frag: k = n = qq*32 + lhi*8 + m, from packed regs via bpermute
      const unsigned int e0 = __builtin_amdgcn_ds_bpermute(A0, pkd[4 * qq + 0]);
      const unsigned int o0 = __builtin_amdgcn_ds_bpermute(A0, pkd[4 * qq + 2]);
      const unsigned int e1 = __builtin_amdgcn_ds_bpermute(A0, pkd[4 * qq + 1]);
      const unsigned int o1 = __builtin_amdgcn_ds_bpermute(A0, pkd[4 * qq + 3]);
      const unsigned int e2 = __builtin_amdgcn_ds_bpermute(A1, pkd[4 * qq + 0]);
      const unsigned int o2 = __builtin_amdgcn_ds_bpermute(A1, pkd[4 * qq + 2]);
      const unsigned int e3 = __builtin_amdgcn_ds_bpermute(A1, pkd[4 * qq + 1]);
      const unsigned int o3 = __builtin_amdgcn_ds_bpermute(A1, pkd[4 * qq + 3]);
      union { unsigned int u[4]; short8v v; } bp_;
      bp_.u[0] = lo ? e0 : o0;
      bp_.u[1] = lo ? e1 : o1;
      bp_.u[2] = lo ? e2 : o2;
      bp_.u[3] = lo ? e3 : o3;
      const short8v bp = bp_.v;
      const short8v ae = *(const short8v*)(sE + qq * 512 + lane * 8);
      __builtin_amdgcn_s_setprio(1);
      accE = __builtin_amdgcn_mfma_f32_16x16x32_bf16(ae, bp, accE, 0, 0, 0);
#pragma unroll
      for (int ct = 0; ct < 16; ct++) {
        const short8v af = *(const short8v*)(bbuf + ct * 512 + lane * 8);
        acc[ct] =
            __builtin_amdgcn_mfma_f32_16x16x32_bf16(af, bp, acc[ct], 0, 0, 0);
      }
      __builtin_amdgcn_s_setprio(0);
    }
  }
  __builtin_amdgcn_sched_barrier(0);

  // ---- epilogue (all lane-local): o/psum + bo + resid, LN, float4 store
  const float inv = 1.f / accE[0];
  float s1 = 0.f, s2 = 0.f;
#pragma unroll
  for (int ct = 0; ct < 16; ct++) {
    const float4 rz = *(const float4*)(Srow + ct * 16 + lhi * 4);
    const float4 b4 = *(const float4*)(bo + ct * 16 + lhi * 4);
    f32x4 v;
    v[0] = acc[ct][0] * inv + b4.x + rz.x;
    v[1] = acc[ct][1] * inv + b4.y + rz.y;
    v[2] = acc[ct][2] * inv + b4.z + rz.z;
    v[3] = acc[ct][3] * inv + b4.w + rz.w;
#pragma unroll
    for (int g = 0; g < 4; g++) {
      s1 += v[g];
      s2 = fmaf(v[g], v[g], s2);
    }
    acc[ct] = v;
  }
  s1 += __shfl_xor(s1, 16); s2 += __shfl_xor(s2, 16);
  s1 += __shfl_xor(s1, 32); s2 += __shfl_xor(s2, 32);
  const float mean = s1 * (1.f / 256.f);
  const float rstd = rsqrtf(s2 * (1.f / 256.f) - mean * mean + 1e-5f);
  float* Orow = out + base + (size_t)(w * 16 + l16) * 256;
#pragma unroll
  for (int ct = 0; ct < 16; ct++) {
    const float4 g4 = *(const float4*)(gamma + ct * 16 + lhi * 4);
    const float4 be4 = *(const float4*)(beta + ct * 16 + lhi * 4);
    float4 ov;
    ov.x = (acc[ct][0] - mean) * rstd * g4.x + be4.x;
    ov.y = (acc[ct][1] - mean) * rstd * g4.y + be4.y;
    ov.z = (acc[ct][2] - mean) * rstd * g4.z + be4.z;
    ov.w = (acc[ct][3] - mean) * rstd * g4.w + be4.w;
    *(float4*)(Orow + ct * 16 + lhi * 4) = ov;
  }
}

extern "C" void kernel_launch(void* const* d_in, const int* in_sizes, int n_in,
                              void* d_out, int out_size, void* d_ws, size_t ws_size,
                              hipStream_t stream) {
  const float* hs    = (const float*)d_in[0];
  const float* S     = (const float*)d_in[1];
  const float* Wq    = (const float*)d_in[2];
  const float* bq    = (const float*)d_in[3];
  const float* Wk    = (const float*)d_in[4];
  const float* bk    = (const float*)d_in[5];
  const float* Wv    = (const float*)d_in[6];
  const float* bv    = (const float*)d_in[7];
  const float* Wo    = (const float*)d_in[8];
  const float* bo    = (const float*)d_in[9];
  const float* gamma = (const float*)d_in[10];
  const float* beta  = (const float*)d_in[11];

  unsigned short* W2c = (unsigned short*)d_ws;          // 8*256*256 bf16 = 1MB
  unsigned short* V2c = W2c + 8 * 256 * 256;            // 1MB
  float* WA  = (float*)(V2c + 8 * 256 * 256);           // 256KB
  float* WB  = WA + 256 * 256;                          // 256KB
  float* wb2 = WB + 256 * 256;                          // 1KB
  float* cq  = wb2 + 256;
  float* cv  = cq + 256;
  float* cb  = cv + 256;
  float* ebn = cb + 256;                                // 8*256 f32

  make_w<<<256, 256, 0, stream>>>(Wq, Wk, Wv, Wo, bq, bk, bv, WA, WB, wb2, cq,
                                  cv, cb);
  bn_k<<<8, 256, 0, stream>>>(hs, wb2, cb, ebn);
  prep2<<<256, 256, 0, stream>>>(hs, WA, WB, cq, cv, ebn, W2c, V2c);
  pair_attn13<<<8192, 256, 0, stream>>>(S, bo, gamma, beta, ebn, W2c, V2c,
                                        (float*)d_out);
}

// Round 16
// 533.312 us; speedup vs baseline: 1.1407x; 1.0441x over previous
//
#include <hip/hip_runtime.h>
#include <hip/hip_bf16.h>

typedef __attribute__((ext_vector_type(8))) short short8v;
typedef __attribute__((ext_vector_type(4))) float f32x4;
typedef __attribute__((ext_vector_type(8))) unsigned short us8;
typedef const __attribute__((address_space(1))) void* gas_t;
typedef __attribute__((address_space(3))) void* las_t;

__device__ __forceinline__ unsigned short f2bf(float f) {
  union { __hip_bfloat16 h; unsigned short u; } c;
  c.h = __float2bfloat16(f);
  return c.u;
}
__device__ __forceinline__ unsigned int f2bf2(float lo, float hi) {
  union { __hip_bfloat162 h; unsigned int u; } c;
  c.h = __float22bfloat162_rn(make_float2(lo, hi));
  return c.u;
}

// WA = (Wq@Wk^T)/16, WB = Wv@Wo, wb2 = (Wq@bk)/16, cq = (bq@Wk^T)/16,
// cv = bv@Wo, cb = (bk.bq)/16
__global__ __launch_bounds__(256) void make_w(
    const float* __restrict__ Wq, const float* __restrict__ Wk,
    const float* __restrict__ Wv, const float* __restrict__ Wo,
    const float* __restrict__ bq, const float* __restrict__ bk,
    const float* __restrict__ bv, float* __restrict__ WA,
    float* __restrict__ WB, float* __restrict__ wb2,
    float* __restrict__ cq, float* __restrict__ cv, float* __restrict__ cb) {
  __shared__ float wq[256], wv[256], bqs[256], bvs[256];
  const int i = blockIdx.x, t = threadIdx.x;
  wq[t] = Wq[i * 256 + t];
  wv[t] = Wv[i * 256 + t];
  bqs[t] = bq[t];
  bvs[t] = bv[t];
  __syncthreads();
  float sa = 0.f, sb = 0.f;
#pragma unroll 8
  for (int d = 0; d < 256; d++) {
    sa = fmaf(wq[d], Wk[t * 256 + d], sa);  // WA[i][t]
    sb = fmaf(wv[d], Wo[d * 256 + t], sb);  // WB[i][t]
  }
  WA[i * 256 + t] = sa * 0.0625f;
  WB[i * 256 + t] = sb;
  if (t == 0) {
    float s = 0.f;
#pragma unroll 8
    for (int d = 0; d < 256; d++) s = fmaf(wq[d], bk[d], s);
    wb2[i] = s * 0.0625f;
  }
  if (i == 0) {
    float s1 = 0.f, s2 = 0.f;
#pragma unroll 8
    for (int d = 0; d < 256; d++) {
      s1 = fmaf(bqs[d], Wk[t * 256 + d], s1);
      s2 = fmaf(bvs[d], Wo[d * 256 + t], s2);
    }
    cq[t] = s1 * 0.0625f;
    cv[t] = s2;
    if (t == 0) {
      float s = 0.f;
      for (int d = 0; d < 256; d++) s = fmaf(bk[d], bqs[d], s);
      cb[0] = s * 0.0625f;
    }
  }
}

// bn[b][n] = hs[b][n]@wb2 + cb  (softmax-axis bias, added pre-exp)
__global__ __launch_bounds__(256) void bn_k(
    const float* __restrict__ hs, const float* __restrict__ wb2,
    const float* __restrict__ cb, float* __restrict__ bn) {
  __shared__ float w2s[256];
  const int b = blockIdx.x, t = threadIdx.x;
  w2s[t] = wb2[t];
  __syncthreads();
  const float* row = hs + (size_t)(b * 256 + t) * 256;
  float s = cb[0];
#pragma unroll 8
  for (int d = 0; d < 256; d++) s = fmaf(row[d], w2s[d], s);
  bn[b * 256 + t] = s;
}

// A-operand panels, chunk-major, MFMA-A-fragment-contiguous:
//   chunk layout = [tile:16][lhi:4][l16:16][j:8] bf16 (16KB), lane reads 16B
//   at tile*1024B + lane*16B.
// W2c: element (n,d): kc=d>>5, tile=n>>4, lhi=(d>>3)&3, l16=n&15, j=d&7
// V2c: element (c,n): kc=n>>5, tile=c>>4, lhi=(n>>3)&3, l16=c&15, j=n&7
__global__ __launch_bounds__(256) void prep2(
    const float* __restrict__ hs, const float* __restrict__ WA,
    const float* __restrict__ WB, const float* __restrict__ cq,
    const float* __restrict__ cv, unsigned short* __restrict__ W2c,
    unsigned short* __restrict__ V2c) {
  __shared__ float rows[8][256];
  const int tid = threadIdx.x;
  const int g0 = blockIdx.x * 8;
#pragma unroll
  for (int j = 0; j < 8; j++) rows[j][tid] = hs[(size_t)(g0 + j) * 256 + tid];
  __syncthreads();
  const float cqv = cq[tid], cvv = cv[tid];
  float aq[8], av[8];
#pragma unroll
  for (int j = 0; j < 8; j++) { aq[j] = cqv; av[j] = cvv; }
#pragma unroll 8
  for (int i = 0; i < 256; i++) {
    const float wa = WA[i * 256 + tid];
    const float wb = WB[i * 256 + tid];
#pragma unroll
    for (int j = 0; j < 8; j++) {
      aq[j] = fmaf(rows[j][i], wa, aq[j]);
      av[j] = fmaf(rows[j][i], wb, av[j]);
    }
  }
  const int bb = g0 >> 8, n0 = g0 & 255;
  // W2c: thread holds (n = n0..n0+7, d = tid)
  {
    const int kc = tid >> 5, lh = (tid >> 3) & 3, j8 = tid & 7;
    unsigned short* dst = W2c + bb * 65536 + kc * 8192 + (n0 >> 4) * 512 +
                          lh * 128 + (n0 & 15) * 8 + j8;
#pragma unroll
    for (int jj = 0; jj < 8; jj++) dst[jj * 8] = f2bf(aq[jj]);
  }
  // V2c: thread holds (c = tid, n = n0..n0+7)
  {
    const int kc = n0 >> 5, lh = (n0 >> 3) & 3;
    us8 vp;
#pragma unroll
    for (int j = 0; j < 8; j++) vp[j] = f2bf(av[j]);
    *(us8*)(V2c + bb * 65536 + kc * 8192 + (tid >> 4) * 512 + lh * 128 +
            (tid & 15) * 8) = vp;
  }
}

// Stage one wave-quarter (4KB) of a 16KB A-chunk into LDS (identity copy).
__device__ __forceinline__ void stage_b(const unsigned short* src,
                                        unsigned short* lds, int lane) {
#pragma unroll
  for (int i = 0; i < 4; i++)
    __builtin_amdgcn_global_load_lds((gas_t)(src + i * 512 + lane * 8),
                                     (las_t)(lds + i * 512), 16, 0, 0);
}

// Swapped-operand fused kernel: ring-3 chunk pipeline, stage-2-ahead,
// counted vmcnt(4); 3 blocks/CU (49KB LDS). scores^T = mfma(W2, S^T);
// P in registers; o^T = mfma(V2^T, P^T); denominator = 2 shuffles.
__global__ __launch_bounds__(256, 3) void pair_attn14(
    const float* __restrict__ S, const float* __restrict__ bo,
    const float* __restrict__ gamma, const float* __restrict__ beta,
    const float* __restrict__ bn, const unsigned short* __restrict__ W2c,
    const unsigned short* __restrict__ V2c, float* __restrict__ out) {
  __shared__ unsigned short sB[3][8192];  // 3 x 16KB A-chunk ring
  __shared__ float sBn[256];              // bn values (1KB)

  const int tid = threadIdx.x;
  const int w = tid >> 6;
  const int lane = tid & 63;
  const int l16 = lane & 15;
  const int lhi = lane >> 4;
  // bijective XCD swizzle: 8192 wgs, 8 XCDs -> each XCD owns one batch
  const int bid = blockIdx.x;
  const int idx = (bid & 7) * 1024 + (bid >> 3);
  const int rblk = idx & 3;
  const int lrow = (idx >> 2) & 255;
  const int bat = idx >> 10;

  const size_t base = ((size_t)((bat * 256 + lrow) * 256 + rblk * 64)) * 256;
  const float* Srow = S + base + (size_t)(w * 16 + l16) * 256;  // lane's row

  // ---- S B-frags straight from global (row r, d = kc*32 + lhi*8 + j)
  short8v sf[8];
#pragma unroll
  for (int kc = 0; kc < 8; kc++) {
    const float4 u = *(const float4*)(Srow + kc * 32 + lhi * 8);
    const float4 v = *(const float4*)(Srow + kc * 32 + lhi * 8 + 4);
    us8 p;
    unsigned int* pu = (unsigned int*)&p;
    pu[0] = f2bf2(u.x, u.y);
    pu[1] = f2bf2(u.z, u.w);
    pu[2] = f2bf2(v.x, v.y);
    pu[3] = f2bf2(v.z, v.w);
    sf[kc] = *(short8v*)&p;
  }

  // ---- bn -> LDS (broadcast table for the exp phase)
  sBn[tid] = bn[bat * 256 + tid];

  asm volatile("s_waitcnt lgkmcnt(0)" ::: "memory");
  asm volatile("s_waitcnt vmcnt(0)" ::: "memory");
  __builtin_amdgcn_sched_barrier(0);

  const unsigned short* W2b = W2c + (size_t)bat * 65536;
  const unsigned short* V2b = V2c + (size_t)bat * 65536;

  // prologue: stage chunks 0,1 (ring depth 3, 2 chunks in flight)
  stage_b(W2b + 0 * 8192 + w * 2048, &sB[0][w * 2048], lane);
  stage_b(W2b + 1 * 8192 + w * 2048, &sB[1][w * 2048], lane);

  f32x4 acc[16];
  unsigned int pkd[32];
  float psum = 0.f;
#pragma unroll
  for (int t = 0; t < 16; t++) acc[t] = (f32x4){0.f, 0.f, 0.f, 0.f};

  // bpermute source-lane addresses (bytes): src lane = l16 + 16*lhi_s
  const int A0 = (l16 + ((lhi & 1) * 32)) * 4;
  const int A1 = A0 + 64;
  const bool lo = (lhi < 2);

  // ---- unified 16-chunk pipeline: t=0..7 GEMM-A (over d), 8..15 GEMM-B
#pragma unroll
  for (int t = 0; t < 16; t++) {
    // counted wait: chunk t complete; chunk t+1 may stay in flight.
    if (t < 15) {
      asm volatile("s_waitcnt vmcnt(4)" ::: "memory");
    } else {
      asm volatile("s_waitcnt vmcnt(0)" ::: "memory");
    }
    __builtin_amdgcn_s_barrier();
    if (t + 2 < 16) {  // stage chunk t+2 into ring slot (t+2)%3
      const int t2 = t + 2;
      const unsigned short* src =
          (t2 < 8) ? (W2b + t2 * 8192) : (V2b + (t2 - 8) * 8192);
      stage_b(src + w * 2048, &sB[t2 % 3][w * 2048], lane);
    }
    __builtin_amdgcn_sched_barrier(0);
    const unsigned short* bbuf = &sB[t % 3][0];

    if (t < 8) {
      // GEMM-A: acc[nt] += mfma(W2_tile_nt, S^T_chunk_t)
      __builtin_amdgcn_s_setprio(1);
#pragma unroll
      for (int nt = 0; nt < 16; nt++) {
        const short8v af = *(const short8v*)(bbuf + nt * 512 + lane * 8);
        acc[nt] = __builtin_amdgcn_mfma_f32_16x16x32_bf16(af, sf[t], acc[nt],
                                                          0, 0, 0);
      }
      __builtin_amdgcn_s_setprio(0);
      if (t == 7) {
        // softmax numerators: p = exp(s + bn); denominator = lane-local
        // sum + 2 shuffles (lane's 64 p's tile its whole r-column).
#pragma unroll
        for (int nt = 0; nt < 16; nt++) {
          const f32x4 b4 = *(const f32x4*)(sBn + nt * 16 + lhi * 4);
          const float p0 = __expf(acc[nt][0] + b4[0]);
          const float p1 = __expf(acc[nt][1] + b4[1]);
          const float p2 = __expf(acc[nt][2] + b4[2]);
          const float p3 = __expf(acc[nt][3] + b4[3]);
          psum += (p0 + p1) + (p2 + p3);
          pkd[nt * 2] = f2bf2(p0, p1);
          pkd[nt * 2 + 1] = f2bf2(p2, p3);
          acc[nt] = (f32x4){0.f, 0.f, 0.f, 0.f};
        }
        psum += __shfl_xor(psum, 16);
        psum += __shfl_xor(psum, 32);
      }
    } else {
      const int qq = t - 8;
      // P^T B-frag: k = n = qq*32 + lhi*8 + m, from packed regs via bpermute
      const unsigned int e0 = __builtin_amdgcn_ds_bpermute(A0, pkd[4 * qq + 0]);
      const unsigned int o0 = __builtin_amdgcn_ds_bpermute(A0, pkd[4 * qq + 2]);
      const unsigned int e1 = __builtin_amdgcn_ds_bpermute(A0, pkd[4 * qq + 1]);
      const unsigned int o1 = __builtin_amdgcn_ds_bpermute(A0, pkd[4 * qq + 3]);
      const unsigned int e2 = __builtin_amdgcn_ds_bpermute(A1, pkd[4 * qq + 0]);
      const unsigned int o2 = __builtin_amdgcn_ds_bpermute(A1, pkd[4 * qq + 2]);
      const unsigned int e3 = __builtin_amdgcn_ds_bpermute(A1, pkd[4 * qq + 1]);
      const unsigned int o3 = __builtin_amdgcn_ds_bpermute(A1, pkd[4 * qq + 3]);
      union { unsigned int u[4]; short8v v; } bp_;
      bp_.u[0] = lo ? e0 : o0;
      bp_.u[1] = lo ? e1 : o1;
      bp_.u[2] = lo ? e2 : o2;
      bp_.u[3] = lo ? e3 : o3;
      const short8v bp = bp_.v;
      __builtin_amdgcn_s_setprio(1);
#pragma unroll
      for (int ct = 0; ct < 16; ct++) {
        const short8v af = *(const short8v*)(bbuf + ct * 512 + lane * 8);
        acc[ct] =
            __builtin_amdgcn_mfma_f32_16x16x32_bf16(af, bp, acc[ct], 0, 0, 0);
      }
      __builtin_amdgcn_s_setprio(0);
    }
  }
  __builtin_amdgcn_sched_barrier(0);

  // ---- epilogue (all lane-local): o/psum + bo + resid, LN, float4 store
  const float inv = 1.f / psum;
  float s1 = 0.f, s2 = 0.f;
#pragma unroll
  for (int ct = 0; ct < 16; ct++) {
    const float4 rz = *(const float4*)(Srow + ct * 16 + lhi * 4);
    const float4 b4 = *(const float4*)(bo + ct * 16 + lhi * 4);
    f32x4 v;
    v[0] = acc[ct][0] * inv + b4.x + rz.x;
    v[1] = acc[ct][1] * inv + b4.y + rz.y;
    v[2] = acc[ct][2] * inv + b4.z + rz.z;
    v[3] = acc[ct][3] * inv + b4.w + rz.w;
#pragma unroll
    for (int g = 0; g < 4; g++) {
      s1 += v[g];
      s2 = fmaf(v[g], v[g], s2);
    }
    acc[ct] = v;
  }
  s1 += __shfl_xor(s1, 16); s2 += __shfl_xor(s2, 16);
  s1 += __shfl_xor(s1, 32); s2 += __shfl_xor(s2, 32);
  const float mean = s1 * (1.f / 256.f);
  const float rstd = rsqrtf(s2 * (1.f / 256.f) - mean * mean + 1e-5f);
  float* Orow = out + base + (size_t)(w * 16 + l16) * 256;
#pragma unroll
  for (int ct = 0; ct < 16; ct++) {
    const float4 g4 = *(const float4*)(gamma + ct * 16 + lhi * 4);
    const float4 be4 = *(const float4*)(beta + ct * 16 + lhi * 4);
    float4 ov;
    ov.x = (acc[ct][0] - mean) * rstd * g4.x + be4.x;
    ov.y = (acc[ct][1] - mean) * rstd * g4.y + be4.y;
    ov.z = (acc[ct][2] - mean) * rstd * g4.z + be4.z;
    ov.w = (acc[ct][3] - mean) * rstd * g4.w + be4.w;
    *(float4*)(Orow + ct * 16 + lhi * 4) = ov;
  }
}

extern "C" void kernel_launch(void* const* d_in, const int* in_sizes, int n_in,
                              void* d_out, int out_size, void* d_ws, size_t ws_size,
                              hipStream_t stream) {
  const float* hs    = (const float*)d_in[0];
  const float* S     = (const float*)d_in[1];
  const float* Wq    = (const float*)d_in[2];
  const float* bq    = (const float*)d_in[3];
  const float* Wk    = (const float*)d_in[4];
  const float* bk    = (const float*)d_in[5];
  const float* Wv    = (const float*)d_in[6];
  const float* bv    = (const float*)d_in[7];
  const float* Wo    = (const float*)d_in[8];
  const float* bo    = (const float*)d_in[9];
  const float* gamma = (const float*)d_in[10];
  const float* beta  = (const float*)d_in[11];

  unsigned short* W2c = (unsigned short*)d_ws;          // 8*256*256 bf16 = 1MB
  unsigned short* V2c = W2c + 8 * 256 * 256;            // 1MB
  float* WA  = (float*)(V2c + 8 * 256 * 256);           // 256KB
  float* WB  = WA + 256 * 256;                          // 256KB
  float* wb2 = WB + 256 * 256;                          // 1KB
  float* cq  = wb2 + 256;
  float* cv  = cq + 256;
  float* cb  = cv + 256;
  float* bnp = cb + 256;                                // 8*256 f32

  make_w<<<256, 256, 0, stream>>>(Wq, Wk, Wv, Wo, bq, bk, bv, WA, WB, wb2, cq,
                                  cv, cb);
  bn_k<<<8, 256, 0, stream>>>(hs, wb2, cb, bnp);
  prep2<<<256, 256, 0, stream>>>(hs, WA, WB, cq, cv, W2c, V2c);
  pair_attn14<<<8192, 256, 0, stream>>>(S, bo, gamma, beta, bnp, W2c, V2c,
                                        (float*)d_out);
}

// Round 17
// 513.195 us; speedup vs baseline: 1.1855x; 1.0392x over previous
//
#include <hip/hip_runtime.h>
#include <hip/hip_bf16.h>

typedef __attribute__((ext_vector_type(8))) short short8v;
typedef __attribute__((ext_vector_type(4))) float f32x4;
typedef __attribute__((ext_vector_type(8))) unsigned short us8;
typedef const __attribute__((address_space(1))) void* gas_t;
typedef __attribute__((address_space(3))) void* las_t;

__device__ __forceinline__ unsigned short f2bf(float f) {
  union { __hip_bfloat16 h; unsigned short u; } c;
  c.h = __float2bfloat16(f);
  return c.u;
}
__device__ __forceinline__ unsigned int f2bf2(float lo, float hi) {
  union { __hip_bfloat162 h; unsigned int u; } c;
  c.h = __float22bfloat162_rn(make_float2(lo, hi));
  return c.u;
}

// Transpose Wk (256x256 f32) -> WkT so make_w's reads are coalesced.
__global__ __launch_bounds__(256) void tr_wk(const float* __restrict__ Wk,
                                             float* __restrict__ WkT) {
  __shared__ float sT[64][65];
  const int b = blockIdx.x;  // 16 blocks: 4x4 tiles of 64x64
  const int bi = b >> 2, bj = b & 3;
  const int tid = threadIdx.x;
  const int r4 = tid >> 6, c64 = tid & 63;
#pragma unroll
  for (int p = 0; p < 16; p++) {
    const int row = bi * 64 + p * 4 + r4;
    const int col = bj * 64 + c64;
    sT[c64][p * 4 + r4] = Wk[row * 256 + col];
  }
  __syncthreads();
#pragma unroll
  for (int p = 0; p < 16; p++) {
    const int orow = bj * 64 + p * 4 + r4;  // d index
    const int ocol = bi * 64 + c64;         // t index
    WkT[orow * 256 + ocol] = sT[p * 4 + r4][c64];
  }
}

// WA = (Wq@Wk^T)/16, WB = Wv@Wo, wb2 = (Wq@bk)/16, cq = (bq@Wk^T)/16,
// cv = bv@Wo, cb = (bk.bq)/16   (Wk accessed via WkT -> coalesced)
__global__ __launch_bounds__(256) void make_w(
    const float* __restrict__ WkT, const float* __restrict__ Wq,
    const float* __restrict__ Wv, const float* __restrict__ Wo,
    const float* __restrict__ bq, const float* __restrict__ bk,
    const float* __restrict__ bv, float* __restrict__ WA,
    float* __restrict__ WB, float* __restrict__ wb2,
    float* __restrict__ cq, float* __restrict__ cv, float* __restrict__ cb) {
  __shared__ float wq[256], wv[256], bqs[256], bvs[256];
  const int i = blockIdx.x, t = threadIdx.x;
  wq[t] = Wq[i * 256 + t];
  wv[t] = Wv[i * 256 + t];
  bqs[t] = bq[t];
  bvs[t] = bv[t];
  __syncthreads();
  float sa = 0.f, sb = 0.f;
#pragma unroll 8
  for (int d = 0; d < 256; d++) {
    sa = fmaf(wq[d], WkT[d * 256 + t], sa);  // WA[i][t]
    sb = fmaf(wv[d], Wo[d * 256 + t], sb);   // WB[i][t]
  }
  WA[i * 256 + t] = sa * 0.0625f;
  WB[i * 256 + t] = sb;
  if (t == 0) {
    float s = 0.f;
#pragma unroll 8
    for (int d = 0; d < 256; d++) s = fmaf(wq[d], bk[d], s);
    wb2[i] = s * 0.0625f;
  }
  if (i == 0) {
    float s1 = 0.f, s2 = 0.f;
#pragma unroll 8
    for (int d = 0; d < 256; d++) {
      s1 = fmaf(bqs[d], WkT[d * 256 + t], s1);
      s2 = fmaf(bvs[d], Wo[d * 256 + t], s2);
    }
    cq[t] = s1 * 0.0625f;
    cv[t] = s2;
    if (t == 0) {
      float s = 0.f;
      for (int d = 0; d < 256; d++) s = fmaf(bk[d], bqs[d], s);
      cb[0] = s * 0.0625f;
    }
  }
}

// A-operand panels, chunk-major, MFMA-A-fragment-contiguous:
//   chunk layout = [tile:16][lhi:4][l16:16][j:8] bf16 (16KB), lane reads 16B
//   at tile*1024B + lane*16B.
// W2c: element (n,d): kc=d>>5, tile=n>>4, lhi=(d>>3)&3, l16=n&15, j=d&7
// V2c: element (c,n): kc=n>>5, tile=c>>4, lhi=(n>>3)&3, l16=c&15, j=n&7
// bn[b][n] = hs[n]@wb2 + cb  (softmax-axis bias, added pre-exp)
__global__ __launch_bounds__(256) void prep2(
    const float* __restrict__ hs, const float* __restrict__ WA,
    const float* __restrict__ WB, const float* __restrict__ cq,
    const float* __restrict__ cv, const float* __restrict__ wb2,
    const float* __restrict__ cb, unsigned short* __restrict__ W2c,
    unsigned short* __restrict__ V2c, float* __restrict__ bn) {
  __shared__ float rows[8][256];
  __shared__ float w2s[256];
  const int tid = threadIdx.x;
  const int g0 = blockIdx.x * 8;
#pragma unroll
  for (int j = 0; j < 8; j++) rows[j][tid] = hs[(size_t)(g0 + j) * 256 + tid];
  w2s[tid] = wb2[tid];
  __syncthreads();
  const float cqv = cq[tid], cvv = cv[tid];
  float aq[8], av[8];
#pragma unroll
  for (int j = 0; j < 8; j++) { aq[j] = cqv; av[j] = cvv; }
#pragma unroll 8
  for (int i = 0; i < 256; i++) {
    const float wa = WA[i * 256 + tid];
    const float wb = WB[i * 256 + tid];
#pragma unroll
    for (int j = 0; j < 8; j++) {
      aq[j] = fmaf(rows[j][i], wa, aq[j]);
      av[j] = fmaf(rows[j][i], wb, av[j]);
    }
  }
  const int bb = g0 >> 8, n0 = g0 & 255;
  // W2c: thread holds (n = n0..n0+7, d = tid)
  {
    const int kc = tid >> 5, lh = (tid >> 3) & 3, j8 = tid & 7;
    unsigned short* dst = W2c + bb * 65536 + kc * 8192 + (n0 >> 4) * 512 +
                          lh * 128 + (n0 & 15) * 8 + j8;
#pragma unroll
    for (int jj = 0; jj < 8; jj++) dst[jj * 8] = f2bf(aq[jj]);
  }
  // V2c: thread holds (c = tid, n = n0..n0+7)
  {
    const int kc = n0 >> 5, lh = (n0 >> 3) & 3;
    us8 vp;
#pragma unroll
    for (int j = 0; j < 8; j++) vp[j] = f2bf(av[j]);
    *(us8*)(V2c + bb * 65536 + kc * 8192 + (tid >> 4) * 512 + lh * 128 +
            (tid & 15) * 8) = vp;
  }
  if (tid < 8) {
    float s = 0.f;
    for (int i = 0; i < 256; i++) s = fmaf(rows[tid][i], w2s[i], s);
    bn[bb * 256 + n0 + tid] = s + cb[0];
  }
}

// Stage one wave-quarter (4KB) of a 16KB A-chunk into LDS (identity copy).
__device__ __forceinline__ void stage_b(const unsigned short* src,
                                        unsigned short* lds, int lane) {
#pragma unroll
  for (int i = 0; i < 4; i++)
    __builtin_amdgcn_global_load_lds((gas_t)(src + i * 512 + lane * 8),
                                     (las_t)(lds + i * 512), 16, 0, 0);
}

// Swapped-operand fused kernel: ring-3 chunk pipeline, stage-2-ahead,
// counted vmcnt(4); 3 blocks/CU (49KB LDS). scores^T = mfma(W2, S^T);
// P in registers; o^T = mfma(V2^T, P^T); denominator = 2 shuffles.
__global__ __launch_bounds__(256, 3) void pair_attn14(
    const float* __restrict__ S, const float* __restrict__ bo,
    const float* __restrict__ gamma, const float* __restrict__ beta,
    const float* __restrict__ bn, const unsigned short* __restrict__ W2c,
    const unsigned short* __restrict__ V2c, float* __restrict__ out) {
  __shared__ unsigned short sB[3][8192];  // 3 x 16KB A-chunk ring
  __shared__ float sBn[256];              // bn values (1KB)

  const int tid = threadIdx.x;
  const int w = tid >> 6;
  const int lane = tid & 63;
  const int l16 = lane & 15;
  const int lhi = lane >> 4;
  // bijective XCD swizzle: 8192 wgs, 8 XCDs -> each XCD owns one batch
  const int bid = blockIdx.x;
  const int idx = (bid & 7) * 1024 + (bid >> 3);
  const int rblk = idx & 3;
  const int lrow = (idx >> 2) & 255;
  const int bat = idx >> 10;

  const size_t base = ((size_t)((bat * 256 + lrow) * 256 + rblk * 64)) * 256;
  const float* Srow = S + base + (size_t)(w * 16 + l16) * 256;  // lane's row

  // ---- S B-frags straight from global (row r, d = kc*32 + lhi*8 + j)
  short8v sf[8];
#pragma unroll
  for (int kc = 0; kc < 8; kc++) {
    const float4 u = *(const float4*)(Srow + kc * 32 + lhi * 8);
    const float4 v = *(const float4*)(Srow + kc * 32 + lhi * 8 + 4);
    us8 p;
    unsigned int* pu = (unsigned int*)&p;
    pu[0] = f2bf2(u.x, u.y);
    pu[1] = f2bf2(u.z, u.w);
    pu[2] = f2bf2(v.x, v.y);
    pu[3] = f2bf2(v.z, v.w);
    sf[kc] = *(short8v*)&p;
  }

  // ---- bn -> LDS (broadcast table for the exp phase)
  sBn[tid] = bn[bat * 256 + tid];

  asm volatile("s_waitcnt lgkmcnt(0)" ::: "memory");
  asm volatile("s_waitcnt vmcnt(0)" ::: "memory");
  __builtin_amdgcn_sched_barrier(0);

  const unsigned short* W2b = W2c + (size_t)bat * 65536;
  const unsigned short* V2b = V2c + (size_t)bat * 65536;

  // prologue: stage chunks 0,1 (ring depth 3, 2 chunks in flight)
  stage_b(W2b + 0 * 8192 + w * 2048, &sB[0][w * 2048], lane);
  stage_b(W2b + 1 * 8192 + w * 2048, &sB[1][w * 2048], lane);

  f32x4 acc[16];
  unsigned int pkd[32];
  float psum = 0.f;
#pragma unroll
  for (int t = 0; t < 16; t++) acc[t] = (f32x4){0.f, 0.f, 0.f, 0.f};

  // bpermute source-lane addresses (bytes): src lane = l16 + 16*lhi_s
  const int A0 = (l16 + ((lhi & 1) * 32)) * 4;
  const int A1 = A0 + 64;
  const bool lo = (lhi < 2);

  // ---- unified 16-chunk pipeline: t=0..7 GEMM-A (over d), 8..15 GEMM-B
#pragma unroll
  for (int t = 0; t < 16; t++) {
    // counted wait: chunk t complete; chunk t+1 may stay in flight.
    if (t < 15) {
      asm volatile("s_waitcnt vmcnt(4)" ::: "memory");
    } else {
      asm volatile("s_waitcnt vmcnt(0)" ::: "memory");
    }
    __builtin_amdgcn_s_barrier();
    if (t + 2 < 16) {  // stage chunk t+2 into ring slot (t+2)%3
      const int t2 = t + 2;
      const unsigned short* src =
          (t2 < 8) ? (W2b + t2 * 8192) : (V2b + (t2 - 8) * 8192);
      stage_b(src + w * 2048, &sB[t2 % 3][w * 2048], lane);
    }
    __builtin_amdgcn_sched_barrier(0);
    const unsigned short* bbuf = &sB[t % 3][0];

    if (t < 8) {
      // GEMM-A: acc[nt] += mfma(W2_tile_nt, S^T_chunk_t)
      __builtin_amdgcn_s_setprio(1);
#pragma unroll
      for (int nt = 0; nt < 16; nt++) {
        const short8v af = *(const short8v*)(bbuf + nt * 512 + lane * 8);
        acc[nt] = __builtin_amdgcn_mfma_f32_16x16x32_bf16(af, sf[t], acc[nt],
                                                          0, 0, 0);
      }
      __builtin_amdgcn_s_setprio(0);
      if (t == 7) {
        // softmax numerators: p = exp(s + bn); denominator = lane-local
        // sum + 2 shuffles (lane's 64 p's tile its whole r-column).
#pragma unroll
        for (int nt = 0; nt < 16; nt++) {
          const f32x4 b4 = *(const f32x4*)(sBn + nt * 16 + lhi * 4);
          const float p0 = __expf(acc[nt][0] + b4[0]);
          const float p1 = __expf(acc[nt][1] + b4[1]);
          const float p2 = __expf(acc[nt][2] + b4[2]);
          const float p3 = __expf(acc[nt][3] + b4[3]);
          psum += (p0 + p1) + (p2 + p3);
          pkd[nt * 2] = f2bf2(p0, p1);
          pkd[nt * 2 + 1] = f2bf2(p2, p3);
          acc[nt] = (f32x4){0.f, 0.f, 0.f, 0.f};
        }
        psum += __shfl_xor(psum, 16);
        psum += __shfl_xor(psum, 32);
      }
    } else {
      const int qq = t - 8;
      // P^T B-frag: k = n = qq*32 + lhi*8 + m, from packed regs via bpermute
      const unsigned int e0 = __builtin_amdgcn_ds_bpermute(A0, pkd[4 * qq + 0]);
      const unsigned int o0 = __builtin_amdgcn_ds_bpermute(A0, pkd[4 * qq + 2]);
      const unsigned int e1 = __builtin_amdgcn_ds_bpermute(A0, pkd[4 * qq + 1]);
      const unsigned int o1 = __builtin_amdgcn_ds_bpermute(A0, pkd[4 * qq + 3]);
      const unsigned int e2 = __builtin_amdgcn_ds_bpermute(A1, pkd[4 * qq + 0]);
      const unsigned int o2 = __builtin_amdgcn_ds_bpermute(A1, pkd[4 * qq + 2]);
      const unsigned int e3 = __builtin_amdgcn_ds_bpermute(A1, pkd[4 * qq + 1]);
      const unsigned int o3 = __builtin_amdgcn_ds_bpermute(A1, pkd[4 * qq + 3]);
      union { unsigned int u[4]; short8v v; } bp_;
      bp_.u[0] = lo ? e0 : o0;
      bp_.u[1] = lo ? e1 : o1;
      bp_.u[2] = lo ? e2 : o2;
      bp_.u[3] = lo ? e3 : o3;
      const short8v bp = bp_.v;
      __builtin_amdgcn_s_setprio(1);
#pragma unroll
      for (int ct = 0; ct < 16; ct++) {
        const short8v af = *(const short8v*)(bbuf + ct * 512 + lane * 8);
        acc[ct] =
            __builtin_amdgcn_mfma_f32_16x16x32_bf16(af, bp, acc[ct], 0, 0, 0);
      }
      __builtin_amdgcn_s_setprio(0);
    }
  }
  __builtin_amdgcn_sched_barrier(0);

  // ---- epilogue (all lane-local): o/psum + bo + resid, LN, float4 store
  const float inv = 1.f / psum;
  float s1 = 0.f, s2 = 0.f;
#pragma unroll
  for (int ct = 0; ct < 16; ct++) {
    const float4 rz = *(const float4*)(Srow + ct * 16 + lhi * 4);
    const float4 b4 = *(const float4*)(bo + ct * 16 + lhi * 4);
    f32x4 v;
    v[0] = acc[ct][0] * inv + b4.x + rz.x;
    v[1] = acc[ct][1] * inv + b4.y + rz.y;
    v[2] = acc[ct][2] * inv + b4.z + rz.z;
    v[3] = acc[ct][3] * inv + b4.w + rz.w;
#pragma unroll
    for (int g = 0; g < 4; g++) {
      s1 += v[g];
      s2 = fmaf(v[g], v[g], s2);
    }
    acc[ct] = v;
  }
  s1 += __shfl_xor(s1, 16); s2 += __shfl_xor(s2, 16);
  s1 += __shfl_xor(s1, 32); s2 += __shfl_xor(s2, 32);
  const float mean = s1 * (1.f / 256.f);
  const float rstd = rsqrtf(s2 * (1.f / 256.f) - mean * mean + 1e-5f);
  float* Orow = out + base + (size_t)(w * 16 + l16) * 256;
#pragma unroll
  for (int ct = 0; ct < 16; ct++) {
    const float4 g4 = *(const float4*)(gamma + ct * 16 + lhi * 4);
    const float4 be4 = *(const float4*)(beta + ct * 16 + lhi * 4);
    float4 ov;
    ov.x = (acc[ct][0] - mean) * rstd * g4.x + be4.x;
    ov.y = (acc[ct][1] - mean) * rstd * g4.y + be4.y;
    ov.z = (acc[ct][2] - mean) * rstd * g4.z + be4.z;
    ov.w = (acc[ct][3] - mean) * rstd * g4.w + be4.w;
    *(float4*)(Orow + ct * 16 + lhi * 4) = ov;
  }
}

extern "C" void kernel_launch(void* const* d_in, const int* in_sizes, int n_in,
                              void* d_out, int out_size, void* d_ws, size_t ws_size,
                              hipStream_t stream) {
  const float* hs    = (const float*)d_in[0];
  const float* S     = (const float*)d_in[1];
  const float* Wq    = (const float*)d_in[2];
  const float* bq    = (const float*)d_in[3];
  const float* Wk    = (const float*)d_in[4];
  const float* bk    = (const float*)d_in[5];
  const float* Wv    = (const float*)d_in[6];
  const float* bv    = (const float*)d_in[7];
  const float* Wo    = (const float*)d_in[8];
  const float* bo    = (const float*)d_in[9];
  const float* gamma = (const float*)d_in[10];
  const float* beta  = (const float*)d_in[11];

  unsigned short* W2c = (unsigned short*)d_ws;          // 8*256*256 bf16 = 1MB
  unsigned short* V2c = W2c + 8 * 256 * 256;            // 1MB
  float* WA  = (float*)(V2c + 8 * 256 * 256);           // 256KB
  float* WB  = WA + 256 * 256;                          // 256KB
  float* WkT = WB + 256 * 256;                          // 256KB
  float* wb2 = WkT + 256 * 256;                         // 1KB
  float* cq  = wb2 + 256;
  float* cv  = cq + 256;
  float* cb  = cv + 256;
  float* bnp = cb + 256;                                // 8*256 f32

  tr_wk<<<16, 256, 0, stream>>>(Wk, WkT);
  make_w<<<256, 256, 0, stream>>>(WkT, Wq, Wv, Wo, bq, bk, bv, WA, WB, wb2,
                                  cq, cv, cb);
  prep2<<<256, 256, 0, stream>>>(hs, WA, WB, cq, cv, wb2, cb, W2c, V2c, bnp);
  pair_attn14<<<8192, 256, 0, stream>>>(S, bo, gamma, beta, bnp, W2c, V2c,
                                        (float*)d_out);
}